// Round 13
// baseline (130.406 us; speedup 1.0000x reference)
//
#include <hip/hip_runtime.h>
#include <math.h>

#define BB 16
#define TT 2048
#define CC 32
#define HH 4
#define DD 8
#define ZP 33         // LDS row stride in floats (qkv x-stage)
#define KBS 2056      // K buffer halves (256*8 + 8 pad)
#define VRS 264       // V^T row stride in halves (256 + 8 pad)

typedef __fp16 h2  __attribute__((ext_vector_type(2)));
typedef __fp16 h8  __attribute__((ext_vector_type(8)));
typedef float  fx16 __attribute__((ext_vector_type(16)));
typedef int    i4v __attribute__((ext_vector_type(4)));

__device__ __forceinline__ h2 pkh(float a, float b) {
#if __has_builtin(__builtin_amdgcn_cvt_pkrtz)
    return __builtin_amdgcn_cvt_pkrtz(a, b);
#else
    h2 r; r.x = (__fp16)a; r.y = (__fp16)b; return r;
#endif
}

__device__ __forceinline__ float fexp2(float x) {
#if __has_builtin(__builtin_amdgcn_exp2f)
    return __builtin_amdgcn_exp2f(x);
#else
    return exp2f(x);
#endif
}

__device__ __forceinline__ int h2bits(h2 v) { return __builtin_bit_cast(int, v); }

// S (QK^T C-layout) -> exp -> two B-operand P fragments (verified R7-R12)
__device__ __forceinline__ void makeP(const fx16& S, bool last, int thr, int hi, h8* P) {
    float pe[16];
    #pragma unroll
    for (int r = 0; r < 16; r++) {
        const int ko = (r & 3) + 8 * (r >> 2);
        float sv = S[r];
        if (last) sv = (ko <= thr) ? sv : -INFINITY;
        pe[r] = fexp2(sv);
    }
    int Hh[8];
    #pragma unroll
    for (int i = 0; i < 8; i++) Hh[i] = h2bits(pkh(pe[2*i], pe[2*i+1]));
    #pragma unroll
    for (int s = 0; s < 2; s++) {
        const int b0 = 4 * s;
        int own0 = hi ? Hh[b0+2] : Hh[b0+0];
        int own1 = hi ? Hh[b0+3] : Hh[b0+1];
        int snd0 = hi ? Hh[b0+0] : Hh[b0+2];
        int snd1 = hi ? Hh[b0+1] : Hh[b0+3];
        int rcv0 = __shfl_xor(snd0, 32);
        int rcv1 = __shfl_xor(snd1, 32);
        i4v f;
        f.x = hi ? rcv0 : own0;
        f.y = hi ? rcv1 : own1;
        f.z = hi ? own0 : rcv0;
        f.w = hi ? own1 : rcv1;
        P[s] = __builtin_bit_cast(h8, f);
    }
}

// ---------------- Kernel 1: QKV projection (R12 version, known good) ----------
__global__ __launch_bounds__(256) void qkv_kernel(
    const float* __restrict__ x,
    const float* __restrict__ Wq, const float* __restrict__ bq,
    const float* __restrict__ Wk, const float* __restrict__ bk,
    const float* __restrict__ Wv, const float* __restrict__ bv,
    __fp16* __restrict__ Qo, __fp16* __restrict__ Ko, __fp16* __restrict__ Vo)
{
    __shared__ float Xs[256 * ZP];
    const int tid = threadIdx.x;
    const int m = blockIdx.y;
    const int row0 = blockIdx.x * 256;

    {   // coalesced stage of 256 x-rows (32 KB), padded stride 33
        const float4* xg = (const float4*)(x + (size_t)row0 * CC);
        #pragma unroll
        for (int i = 0; i < 8; i++) {
            const int idx = tid + 256 * i;
            float4 f = xg[idx];
            const int w = idx * 4;
            float* d = &Xs[(w >> 5) * ZP + (w & 31)];
            d[0] = f.x; d[1] = f.y; d[2] = f.z; d[3] = f.w;
        }
    }
    __syncthreads();

    const int row = row0 + tid;
    const int b = row >> 11, t = row & 2047;

    float xr[CC];
    #pragma unroll
    for (int c = 0; c < CC; c++) xr[c] = Xs[tid * ZP + c];

    const float* W    = (m == 0) ? Wq : (m == 1) ? Wk : Wv;
    const float* bias = (m == 0) ? bq : (m == 1) ? bk : bv;

    for (int h = 0; h < HH; h++) {
        const int bh = b * HH + h;
        float o[DD];
        #pragma unroll
        for (int d = 0; d < DD; d++) {
            const int dd = h * DD + d;
            float acc = bias[dd];
            #pragma unroll
            for (int c = 0; c < CC; c++) acc += xr[c] * W[dd * CC + c];
            o[d] = acc;
        }
        if (m == 0) {
            const float qs = 0.3535533905932738f * 1.4426950408889634f;
            i4v qw;
            qw.x = h2bits(pkh(o[0]*qs, o[1]*qs)); qw.y = h2bits(pkh(o[2]*qs, o[3]*qs));
            qw.z = h2bits(pkh(o[4]*qs, o[5]*qs)); qw.w = h2bits(pkh(o[6]*qs, o[7]*qs));
            *(i4v*)(Qo + ((size_t)bh * TT + t) * DD) = qw;
        } else if (m == 1) {
            i4v kw;
            kw.x = h2bits(pkh(o[0], o[1])); kw.y = h2bits(pkh(o[2], o[3]));
            kw.z = h2bits(pkh(o[4], o[5])); kw.w = h2bits(pkh(o[6], o[7]));
            *(i4v*)(Ko + ((size_t)bh * TT + t) * DD) = kw;
        } else {
            __fp16* vt = Vo + (size_t)bh * 9 * TT + t;
            #pragma unroll
            for (int d = 0; d < DD; d++) vt[d * TT] = (__fp16)o[d];
            vt[8 * TT] = (__fp16)1.0f;
        }
    }
}

// ---------------- Kernel 2: MFMA attention, 1 wave = 1 (bh, qgroup) ----------
// 4096 single-wave blocks -> 16 waves/CU (4/SIMD). Tier permutation balances
// round-robin dispatch: tier t=bid>>6, class c=t&15 gets g = {63-c, c, 47-c,
// 16+c} across rounds — every class sums to 126 tiles; heavy tiles first.
// Wave-private LDS staging (K 4.1 KB + V^T 4.6 KB), single Q/O context,
// no prefetch arrays -> ~60 VGPR, no spill at the 128-reg (4 waves/EU) cap.
__global__ __launch_bounds__(64, 4) void attn_kernel(
    const __fp16* __restrict__ Qg, const __fp16* __restrict__ Kg,
    const __fp16* __restrict__ Vg, float* __restrict__ Zw)
{
    __shared__ __align__(16) __fp16 kld[KBS];
    __shared__ __align__(16) __fp16 vld[9 * VRS];

    const int bid  = blockIdx.x;
    const int t    = bid >> 6;
    const int bh   = bid & 63;
    const int r_   = t >> 4, c_ = t & 15;
    const int g    = (r_ == 0) ? (63 - c_) : (r_ == 1) ? c_ : (r_ == 2) ? (47 - c_) : (16 + c_);

    const int lane = threadIdx.x;
    const int qc   = lane & 31;
    const int hi   = lane >> 5;

    const int qbase = 32 * g;
    const int q     = qbase + qc;

    h8 qf;
    {   // B operand: Q^T (pre-scaled); hi half zero (annihilates A garbage)
        h8 qz;
        #pragma unroll
        for (int i = 0; i < 8; i++) qz[i] = (__fp16)0.0f;
        h8 ql = *(const h8*)(Qg + ((size_t)bh * TT + q) * DD);
        qf = hi ? qz : ql;
    }

    fx16 O, zc;
    #pragma unroll
    for (int i = 0; i < 16; i++) { O[i] = 0.0f; zc[i] = 0.0f; }

    const int vrow = (qc < 9) ? qc : 8;     // rows>=9 -> ones row (l trick)
    const int thr  = qc - 4 * hi;

    const __fp16* kgl = Kg + (size_t)bh * TT * DD;
    const __fp16* vgl = Vg + (size_t)bh * 9 * TT;
    const __fp16* kb  = kld + qc * DD;
    const __fp16* vb  = vld + vrow * VRS + 8 * hi;

    const int keys = qbase + 32;
    for (int st = 0; st < keys; st += 256) {
        __syncthreads();
        {   // stage 256 keys: K (4 KB) + V^T rows 0..8 (4.5 KB), wave-private
            const i4v* ks = (const i4v*)(kgl + (size_t)st * DD);
            i4v* kd = (i4v*)kld;
            #pragma unroll
            for (int r = 0; r < 4; r++) kd[lane + 64 * r] = ks[lane + 64 * r];
            #pragma unroll
            for (int r = 0; r < 5; r++) {
                const int i = lane + 64 * r;
                if (i < 288)
                    *(i4v*)(vld + (i >> 5) * VRS + (i & 31) * 8) =
                        *(const i4v*)(vgl + (i >> 5) * TT + st + (i & 31) * 8);
            }
        }
        __syncthreads();

        const int kend = min(st + 256, keys);
        for (int kt = st; kt < kend; kt += 32) {
            h8 kf = *(const h8*)(kb + (kt - st) * DD);
            fx16 S = __builtin_amdgcn_mfma_f32_32x32x16_f16(kf, qf, zc, 0, 0, 0);
            h8 P[2];
            makeP(S, kt == qbase, thr, hi, P);
            #pragma unroll
            for (int s = 0; s < 2; s++) {
                h8 vf = *(const h8*)(vb + (kt - st) + 16 * s);
                O = __builtin_amdgcn_mfma_f32_32x32x16_f16(vf, P[s], O, 0, 0, 0);
            }
        }
    }

    // O regs 0-3 = d0-3 (hi=0) / d4-7 (hi=1); O[4] = l (ones-row). One store.
    const float inv = 1.0f / O[4];
    const int b = bh >> 2, h = bh & 3;
    float* z = Zw + ((size_t)b * TT + q) * CC + h * DD + 4 * hi;
    *(float4*)z = make_float4(O[0]*inv, O[1]*inv, O[2]*inv, O[3]*inv);
}

// ---------------- Kernel 3: output projection (ws -> d_out, R7-proven) -------
__global__ __launch_bounds__(256) void proj_kernel(
    const float* __restrict__ Zw, const float* __restrict__ Wp,
    const float* __restrict__ bp, float* __restrict__ out)
{
    const int row = blockIdx.x * 256 + threadIdx.x;
    const int oc = blockIdx.y;

    float zr[CC];
    const float4* zp = (const float4*)(Zw + (size_t)row * CC);
    #pragma unroll
    for (int i = 0; i < CC / 4; i++) {
        float4 f = zp[i];
        zr[4*i+0] = f.x; zr[4*i+1] = f.y; zr[4*i+2] = f.z; zr[4*i+3] = f.w;
    }

    float o[DD];
    #pragma unroll
    for (int d = 0; d < DD; d++) {
        const int dd = oc * DD + d;
        float acc = bp[dd];
        #pragma unroll
        for (int c = 0; c < CC; c++) acc += zr[c] * Wp[dd * CC + c];
        o[d] = acc;
    }

    float* dst = out + (size_t)row * CC + oc * DD;
    ((float4*)dst)[0] = make_float4(o[0], o[1], o[2], o[3]);
    ((float4*)dst)[1] = make_float4(o[4], o[5], o[6], o[7]);
}

extern "C" void kernel_launch(void* const* d_in, const int* in_sizes, int n_in,
                              void* d_out, int out_size, void* d_ws, size_t ws_size,
                              hipStream_t stream) {
    const float* x  = (const float*)d_in[0];
    const float* Wq = (const float*)d_in[1];
    const float* bq = (const float*)d_in[2];
    const float* Wk = (const float*)d_in[3];
    const float* bk = (const float*)d_in[4];
    const float* Wv = (const float*)d_in[5];
    const float* bv = (const float*)d_in[6];
    const float* Wp = (const float*)d_in[7];
    const float* bp = (const float*)d_in[8];
    float* out = (float*)d_out;

    const size_t NE = (size_t)BB * HH * TT * DD;       // 1M
    __fp16* Qh = (__fp16*)d_ws;                        // 2 MB (pre-scaled)
    __fp16* Kh = Qh + NE;                              // 2 MB
    __fp16* Vt = Kh + NE;                              // 2.25 MB  [bh][9][T]
    float*  Zw = (float*)(Vt + (size_t)BB * HH * 9 * TT);  // 4 MB

    qkv_kernel<<<dim3(BB * TT / 256, 3), 256, 0, stream>>>(x, Wq, bq, Wk, bk, Wv, bv, Qh, Kh, Vt);
    attn_kernel<<<dim3(64 * 64), 64, 0, stream>>>(Qh, Kh, Vt, Zw);
    proj_kernel<<<dim3(BB * TT / 256, 4), 256, 0, stream>>>(Zw, Wp, bp, out);
}

// Round 14
// 123.516 us; speedup vs baseline: 1.0558x; 1.0558x over previous
//
#include <hip/hip_runtime.h>
#include <math.h>

#define BB 16
#define TT 2048
#define CC 32
#define HH 4
#define DD 8

#define KBS 2056      // per-wave K buffer stride in halves (256*8 + 8 pad)
#define VRS 264       // V^T row stride in halves (256 + 8 pad)
#define VBS (9 * VRS) // per-wave V buffer halves
#define ZP 33         // LDS row stride in floats

typedef __fp16 h2  __attribute__((ext_vector_type(2)));
typedef __fp16 h8  __attribute__((ext_vector_type(8)));
typedef float  fx16 __attribute__((ext_vector_type(16)));
typedef int    i4v __attribute__((ext_vector_type(4)));

__device__ __forceinline__ h2 pkh(float a, float b) {
#if __has_builtin(__builtin_amdgcn_cvt_pkrtz)
    return __builtin_amdgcn_cvt_pkrtz(a, b);
#else
    h2 r; r.x = (__fp16)a; r.y = (__fp16)b; return r;
#endif
}

__device__ __forceinline__ float fexp2(float x) {
#if __has_builtin(__builtin_amdgcn_exp2f)
    return __builtin_amdgcn_exp2f(x);
#else
    return exp2f(x);
#endif
}

__device__ __forceinline__ int h2bits(h2 v) { return __builtin_bit_cast(int, v); }

// S (QK^T C-layout) -> exp -> two B-operand P fragments (verified R7-R13)
__device__ __forceinline__ void makeP(const fx16& S, bool last, int thr, int hi, h8* P) {
    float pe[16];
    #pragma unroll
    for (int r = 0; r < 16; r++) {
        const int ko = (r & 3) + 8 * (r >> 2);
        float sv = S[r];
        if (last) sv = (ko <= thr) ? sv : -INFINITY;
        pe[r] = fexp2(sv);
    }
    int Hh[8];
    #pragma unroll
    for (int i = 0; i < 8; i++) Hh[i] = h2bits(pkh(pe[2*i], pe[2*i+1]));
    #pragma unroll
    for (int s = 0; s < 2; s++) {
        const int b0 = 4 * s;
        int own0 = hi ? Hh[b0+2] : Hh[b0+0];
        int own1 = hi ? Hh[b0+3] : Hh[b0+1];
        int snd0 = hi ? Hh[b0+0] : Hh[b0+2];
        int snd1 = hi ? Hh[b0+1] : Hh[b0+3];
        int rcv0 = __shfl_xor(snd0, 32);
        int rcv1 = __shfl_xor(snd1, 32);
        i4v f;
        f.x = hi ? rcv0 : own0;
        f.y = hi ? rcv1 : own1;
        f.z = hi ? own0 : rcv0;
        f.w = hi ? own1 : rcv1;
        P[s] = __builtin_bit_cast(h8, f);
    }
}

// ---------------- Kernel 1: QKV projection (y=3, looped heads, R12-proven) ----
__global__ __launch_bounds__(256) void qkv_kernel(
    const float* __restrict__ x,
    const float* __restrict__ Wq, const float* __restrict__ bq,
    const float* __restrict__ Wk, const float* __restrict__ bk,
    const float* __restrict__ Wv, const float* __restrict__ bv,
    __fp16* __restrict__ Qo, __fp16* __restrict__ Ko, __fp16* __restrict__ Vo)
{
    __shared__ float Xs[256 * ZP];
    const int tid = threadIdx.x;
    const int m = blockIdx.y;
    const int row0 = blockIdx.x * 256;

    {   // coalesced stage of 256 x-rows (32 KB), padded stride 33
        const float4* xg = (const float4*)(x + (size_t)row0 * CC);
        #pragma unroll
        for (int i = 0; i < 8; i++) {
            const int idx = tid + 256 * i;
            float4 f = xg[idx];
            const int w = idx * 4;
            float* d = &Xs[(w >> 5) * ZP + (w & 31)];
            d[0] = f.x; d[1] = f.y; d[2] = f.z; d[3] = f.w;
        }
    }
    __syncthreads();

    const int row = row0 + tid;
    const int b = row >> 11, t = row & 2047;

    float xr[CC];
    #pragma unroll
    for (int c = 0; c < CC; c++) xr[c] = Xs[tid * ZP + c];

    const float* W    = (m == 0) ? Wq : (m == 1) ? Wk : Wv;
    const float* bias = (m == 0) ? bq : (m == 1) ? bk : bv;

    for (int h = 0; h < HH; h++) {
        const int bh = b * HH + h;
        float o[DD];
        #pragma unroll
        for (int d = 0; d < DD; d++) {
            const int dd = h * DD + d;
            float acc = bias[dd];
            #pragma unroll
            for (int c = 0; c < CC; c++) acc += xr[c] * W[dd * CC + c];
            o[d] = acc;
        }
        if (m == 0) {
            const float qs = 0.3535533905932738f * 1.4426950408889634f;
            i4v qw;
            qw.x = h2bits(pkh(o[0]*qs, o[1]*qs)); qw.y = h2bits(pkh(o[2]*qs, o[3]*qs));
            qw.z = h2bits(pkh(o[4]*qs, o[5]*qs)); qw.w = h2bits(pkh(o[6]*qs, o[7]*qs));
            *(i4v*)(Qo + ((size_t)bh * TT + t) * DD) = qw;
        } else if (m == 1) {
            i4v kw;
            kw.x = h2bits(pkh(o[0], o[1])); kw.y = h2bits(pkh(o[2], o[3]));
            kw.z = h2bits(pkh(o[4], o[5])); kw.w = h2bits(pkh(o[6], o[7]));
            *(i4v*)(Ko + ((size_t)bh * TT + t) * DD) = kw;
        } else {
            __fp16* vt = Vo + (size_t)bh * 9 * TT + t;
            #pragma unroll
            for (int d = 0; d < DD; d++) vt[d * TT] = (__fp16)o[d];
            vt[8 * TT] = (__fp16)1.0f;
        }
    }
}

// ---------------- Kernel 2: fused attention + projection (R10 structure) -----
// Block 256 thr = 4 waves = 4 heads; EACH WAVE owns the antithetic qgroup pair
// {ip, 63-ip} = exactly 65 tiles/wave, all waves busy start-to-finish; wave-
// private staging, register prefetch, no K-loop barriers. R14 delta vs R10:
// zbuf ALIASES KsS (dead after K-loop) -> LDS 43.9->35.5 KB -> 4 blocks/CU by
// LDS; launch_bounds(256,3) keeps VGPR cap ~170 (no R11-style spill).
__global__ __launch_bounds__(256, 3) void attn_kernel(
    const __fp16* __restrict__ Qg, const __fp16* __restrict__ Kg,
    const __fp16* __restrict__ Vg,
    const float* __restrict__ Wp, const float* __restrict__ bp,
    float* __restrict__ out)
{
    __shared__ __align__(16) __fp16 KsS[4 * KBS];   // K staging; reused as zbuf
    __shared__ __align__(16) __fp16 VtS[4 * VBS];
    float* zbuf = (float*)KsS;                       // 64*ZP*4B = 8.4KB <= 16.4KB

    const int tid  = threadIdx.x;
    const int b    = blockIdx.x & 15;
    const int ip   = blockIdx.x >> 4;       // pair index 0..31
    const int h    = tid >> 6;              // wave = head
    const int lane = tid & 63;
    const int qc   = lane & 31;
    const int hi   = lane >> 5;

    const int bh  = b * HH + h;
    const int qb1 = 32 * ip;                // light qgroup base
    const int qb2 = 32 * (63 - ip);         // heavy qgroup base
    const int keys_needed = qb2 + 32;
    const int nst = (keys_needed + 255) >> 8;

    h8 qf1, qf2;
    {   // B operands: Q^T (pre-scaled); hi half zero (annihilates A garbage)
        h8 qz;
        #pragma unroll
        for (int i = 0; i < 8; i++) qz[i] = (__fp16)0.0f;
        h8 qa = *(const h8*)(Qg + ((size_t)bh * TT + qb1 + qc) * DD);
        h8 qb = *(const h8*)(Qg + ((size_t)bh * TT + qb2 + qc) * DD);
        qf1 = hi ? qz : qa;
        qf2 = hi ? qz : qb;
    }

    fx16 O1, O2, zc;
    #pragma unroll
    for (int i = 0; i < 16; i++) { O1[i] = 0.0f; O2[i] = 0.0f; zc[i] = 0.0f; }

    const int vrow = (qc < 9) ? qc : 8;     // rows>=9 -> ones row (l trick)
    const int thr  = qc - 4 * hi;

    const __fp16* kgl = Kg + (size_t)bh * TT * DD;
    const __fp16* vgl = Vg + (size_t)bh * 9 * TT;
    __fp16* kld = KsS + h * KBS;            // wave-private
    __fp16* vld = VtS + h * VBS;
    const __fp16* kb = kld + qc * DD;
    const __fp16* vb = vld + vrow * VRS + 8 * hi;

    i4v kpre[4], vpre[5];
    {   // prefetch super-tile 0
        const i4v* ks = (const i4v*)kgl;
        #pragma unroll
        for (int r = 0; r < 4; r++) kpre[r] = ks[lane + 64 * r];
        #pragma unroll
        for (int r = 0; r < 5; r++) {
            int i = lane + 64 * r; if (i > 287) i = 287;
            vpre[r] = *(const i4v*)(vgl + (i >> 5) * TT + (i & 31) * 8);
        }
    }

    for (int sti = 0; sti < nst; sti++) {
        const int st = sti * 256;
        {   // commit prefetched tile to wave-private LDS
            i4v* kd = (i4v*)kld;
            #pragma unroll
            for (int r = 0; r < 4; r++) kd[lane + 64 * r] = kpre[r];
            #pragma unroll
            for (int r = 0; r < 5; r++) {
                const int i = lane + 64 * r;
                if (i < 288) *(i4v*)(vld + (i >> 5) * VRS + (i & 31) * 8) = vpre[r];
            }
        }
        if (sti + 1 < nst) {   // issue next tile's global loads (overlap compute)
            const int st2 = st + 256;
            const i4v* ks = (const i4v*)(kgl + (size_t)st2 * DD);
            #pragma unroll
            for (int r = 0; r < 4; r++) kpre[r] = ks[lane + 64 * r];
            #pragma unroll
            for (int r = 0; r < 5; r++) {
                int i = lane + 64 * r; if (i > 287) i = 287;
                vpre[r] = *(const i4v*)(vgl + (i >> 5) * TT + st2 + (i & 31) * 8);
            }
        }

        const int kend = min(st + 256, keys_needed);
        for (int kt = st; kt < kend; kt += 32) {
            const bool a1 = (kt <= qb1);            // wave-uniform
            h8 kf = *(const h8*)(kb + (kt - st) * DD);

            h8 P1[2], P2[2];
            if (a1) {
                fx16 S = __builtin_amdgcn_mfma_f32_32x32x16_f16(kf, qf1, zc, 0, 0, 0);
                makeP(S, kt == qb1, thr, hi, P1);
            }
            {
                fx16 S = __builtin_amdgcn_mfma_f32_32x32x16_f16(kf, qf2, zc, 0, 0, 0);
                makeP(S, kt == qb2, thr, hi, P2);
            }
            #pragma unroll
            for (int s = 0; s < 2; s++) {
                h8 vf = *(const h8*)(vb + (kt - st) + 16 * s);
                if (a1) O1 = __builtin_amdgcn_mfma_f32_32x32x16_f16(vf, P1[s], O1, 0, 0, 0);
                O2 = __builtin_amdgcn_mfma_f32_32x32x16_f16(vf, P2[s], O2, 0, 0, 0);
            }
        }
    }

    __syncthreads();   // all waves done reading KsS before it becomes zbuf

    {   // z -> LDS: O[4] = l (ones-row); regs 0-3 = d0-3 (hi=0) / d4-7 (hi=1)
        const float i1 = 1.0f / O1[4], i2 = 1.0f / O2[4];
        float* z1 = &zbuf[qc * ZP + h * DD + 4 * hi];
        float* z2 = &zbuf[(32 + qc) * ZP + h * DD + 4 * hi];
        z1[0] = O1[0]*i1; z1[1] = O1[1]*i1; z1[2] = O1[2]*i1; z1[3] = O1[3]*i1;
        z2[0] = O2[0]*i2; z2[1] = O2[1]*i2; z2[2] = O2[2]*i2; z2[3] = O2[3]*i2;
    }
    __syncthreads();

    {   // in-block projection: wave = 8-col output segment (uniform Wp -> s_loads)
        const int seg = tid >> 6;
        const int r = tid & 63;             // rows 0-31 -> qg ip, 32-63 -> qg 63-ip
        float zr[CC];
        #pragma unroll
        for (int c = 0; c < CC; c++) zr[c] = zbuf[r * ZP + c];
        float o[DD];
        #pragma unroll
        for (int d = 0; d < DD; d++) {
            const int dd = seg * DD + d;
            float acc = bp[dd];
            #pragma unroll
            for (int c = 0; c < CC; c++) acc += zr[c] * Wp[dd * CC + c];
            o[d] = acc;
        }
        const int qglob = (r < 32) ? (ip * 32 + r) : ((63 - ip) * 32 + (r - 32));
        float* dst = out + ((size_t)b * TT + qglob) * CC + seg * DD;
        ((float4*)dst)[0] = make_float4(o[0], o[1], o[2], o[3]);
        ((float4*)dst)[1] = make_float4(o[4], o[5], o[6], o[7]);
    }
}

extern "C" void kernel_launch(void* const* d_in, const int* in_sizes, int n_in,
                              void* d_out, int out_size, void* d_ws, size_t ws_size,
                              hipStream_t stream) {
    const float* x  = (const float*)d_in[0];
    const float* Wq = (const float*)d_in[1];
    const float* bq = (const float*)d_in[2];
    const float* Wk = (const float*)d_in[3];
    const float* bk = (const float*)d_in[4];
    const float* Wv = (const float*)d_in[5];
    const float* bv = (const float*)d_in[6];
    const float* Wp = (const float*)d_in[7];
    const float* bp = (const float*)d_in[8];
    float* out = (float*)d_out;

    const size_t NE = (size_t)BB * HH * TT * DD;   // 1M
    __fp16* Qh = (__fp16*)d_ws;                    // 2 MB (pre-scaled)
    __fp16* Kh = Qh + NE;                          // 2 MB
    __fp16* Vt = Kh + NE;                          // 2.25 MB  [bh][9][T]

    qkv_kernel<<<dim3(BB * TT / 256, 3), 256, 0, stream>>>(x, Wq, bq, Wk, bk, Wv, bv, Qh, Kh, Vt);
    attn_kernel<<<dim3(BB * 32), 256, 0, stream>>>(Qh, Kh, Vt, Wp, bp, out);
}

// Round 15
// 113.443 us; speedup vs baseline: 1.1495x; 1.0888x over previous
//
#include <hip/hip_runtime.h>
#include <math.h>

#define BB 16
#define TT 2048
#define CC 32
#define HH 4
#define DD 8

#define KBS 2056      // per-wave K buffer stride in halves (256*8 + 8 pad)
#define VRS 264       // V^T row stride in halves (256 + 8 pad)
#define VBS (9 * VRS) // per-wave V buffer halves
#define ZP 33         // LDS row stride in floats

typedef __fp16 h2  __attribute__((ext_vector_type(2)));
typedef __fp16 h8  __attribute__((ext_vector_type(8)));
typedef float  fx16 __attribute__((ext_vector_type(16)));
typedef int    i4v __attribute__((ext_vector_type(4)));

__device__ __forceinline__ h2 pkh(float a, float b) {
#if __has_builtin(__builtin_amdgcn_cvt_pkrtz)
    return __builtin_amdgcn_cvt_pkrtz(a, b);
#else
    h2 r; r.x = (__fp16)a; r.y = (__fp16)b; return r;
#endif
}

__device__ __forceinline__ float fexp2(float x) {
#if __has_builtin(__builtin_amdgcn_exp2f)
    return __builtin_amdgcn_exp2f(x);
#else
    return exp2f(x);
#endif
}

__device__ __forceinline__ int h2bits(h2 v) { return __builtin_bit_cast(int, v); }

// S (QK^T C-layout) -> exp -> two B-operand P fragments (verified R7-R14)
__device__ __forceinline__ void makeP(const fx16& S, bool last, int thr, int hi, h8* P) {
    float pe[16];
    #pragma unroll
    for (int r = 0; r < 16; r++) {
        const int ko = (r & 3) + 8 * (r >> 2);
        float sv = S[r];
        if (last) sv = (ko <= thr) ? sv : -INFINITY;
        pe[r] = fexp2(sv);
    }
    int Hh[8];
    #pragma unroll
    for (int i = 0; i < 8; i++) Hh[i] = h2bits(pkh(pe[2*i], pe[2*i+1]));
    #pragma unroll
    for (int s = 0; s < 2; s++) {
        const int b0 = 4 * s;
        int own0 = hi ? Hh[b0+2] : Hh[b0+0];
        int own1 = hi ? Hh[b0+3] : Hh[b0+1];
        int snd0 = hi ? Hh[b0+0] : Hh[b0+2];
        int snd1 = hi ? Hh[b0+1] : Hh[b0+3];
        int rcv0 = __shfl_xor(snd0, 32);
        int rcv1 = __shfl_xor(snd1, 32);
        i4v f;
        f.x = hi ? rcv0 : own0;
        f.y = hi ? rcv1 : own1;
        f.z = hi ? own0 : rcv0;
        f.w = hi ? own1 : rcv1;
        P[s] = __builtin_bit_cast(h8, f);
    }
}

// ---------------- Kernel 1: QKV projection ----------------
// grid (128, 12): y = m*4+h (6144 waves — the parallelism that made R10 best)
// R15 delta: coalesced LDS x-stage (flat float4 loads -> stride-33 rows; row
// read is 2-way bank aliasing = free). One head (8 outs, 256 FMA) per thread.
__global__ __launch_bounds__(256) void qkv_kernel(
    const float* __restrict__ x,
    const float* __restrict__ Wq, const float* __restrict__ bq,
    const float* __restrict__ Wk, const float* __restrict__ bk,
    const float* __restrict__ Wv, const float* __restrict__ bv,
    __fp16* __restrict__ Qo, __fp16* __restrict__ Ko, __fp16* __restrict__ Vo)
{
    __shared__ float Xs[256 * ZP];
    const int tid = threadIdx.x;
    const int m = blockIdx.y >> 2, h = blockIdx.y & 3;
    const int row0 = blockIdx.x * 256;

    {   // coalesced stage of 256 x-rows (32 KB), padded stride 33
        const float4* xg = (const float4*)(x + (size_t)row0 * CC);
        #pragma unroll
        for (int i = 0; i < 8; i++) {
            const int idx = tid + 256 * i;
            float4 f = xg[idx];
            const int w = idx * 4;
            float* d = &Xs[(w >> 5) * ZP + (w & 31)];
            d[0] = f.x; d[1] = f.y; d[2] = f.z; d[3] = f.w;
        }
    }
    __syncthreads();

    const int row = row0 + tid;
    const int b = row >> 11, t = row & 2047;
    const int bh = b * HH + h;

    float xr[CC];
    #pragma unroll
    for (int c = 0; c < CC; c++) xr[c] = Xs[tid * ZP + c];

    const float* W    = (m == 0) ? Wq : (m == 1) ? Wk : Wv;
    const float* bias = (m == 0) ? bq : (m == 1) ? bk : bv;

    float o[DD];
    #pragma unroll
    for (int d = 0; d < DD; d++) {
        const int dd = h * DD + d;
        float acc = bias[dd];
        #pragma unroll
        for (int c = 0; c < CC; c++) acc += xr[c] * W[dd * CC + c];
        o[d] = acc;
    }

    if (m == 0) {
        const float qs = 0.3535533905932738f * 1.4426950408889634f;
        i4v qw;
        qw.x = h2bits(pkh(o[0]*qs, o[1]*qs)); qw.y = h2bits(pkh(o[2]*qs, o[3]*qs));
        qw.z = h2bits(pkh(o[4]*qs, o[5]*qs)); qw.w = h2bits(pkh(o[6]*qs, o[7]*qs));
        *(i4v*)(Qo + ((size_t)bh * TT + t) * DD) = qw;
    } else if (m == 1) {
        i4v kw;
        kw.x = h2bits(pkh(o[0], o[1])); kw.y = h2bits(pkh(o[2], o[3]));
        kw.z = h2bits(pkh(o[4], o[5])); kw.w = h2bits(pkh(o[6], o[7]));
        *(i4v*)(Ko + ((size_t)bh * TT + t) * DD) = kw;
    } else {
        __fp16* vt = Vo + (size_t)bh * 9 * TT + t;
        #pragma unroll
        for (int d = 0; d < DD; d++) vt[d * TT] = (__fp16)o[d];
        vt[8 * TT] = (__fp16)1.0f;     // ones row -> l via MFMA
    }
}

// ---------------- Kernel 2: fused attention + projection (EXACT R10) ---------
// Block 256 thr = 4 waves = 4 heads; each wave owns antithetic qgroup pair
// {ip, 63-ip} = exactly 65 tiles/wave, all waves busy start-to-finish. Wave-
// private staging, register prefetch, no K-loop barriers. Best measured: R10.
__global__ __launch_bounds__(256, 2) void attn_kernel(
    const __fp16* __restrict__ Qg, const __fp16* __restrict__ Kg,
    const __fp16* __restrict__ Vg,
    const float* __restrict__ Wp, const float* __restrict__ bp,
    float* __restrict__ out)
{
    __shared__ __align__(16) __fp16 KsS[4 * KBS];
    __shared__ __align__(16) __fp16 VtS[4 * VBS];
    __shared__ float zbuf[64 * ZP];

    const int tid  = threadIdx.x;
    const int b    = blockIdx.x & 15;
    const int ip   = blockIdx.x >> 4;       // pair index 0..31
    const int h    = tid >> 6;              // wave = head
    const int lane = tid & 63;
    const int qc   = lane & 31;
    const int hi   = lane >> 5;

    const int bh  = b * HH + h;
    const int qb1 = 32 * ip;                // light qgroup base
    const int qb2 = 32 * (63 - ip);         // heavy qgroup base
    const int keys_needed = qb2 + 32;
    const int nst = (keys_needed + 255) >> 8;

    h8 qf1, qf2;
    {   // B operands: Q^T (pre-scaled); hi half zero (annihilates A garbage)
        h8 qz;
        #pragma unroll
        for (int i = 0; i < 8; i++) qz[i] = (__fp16)0.0f;
        h8 qa = *(const h8*)(Qg + ((size_t)bh * TT + qb1 + qc) * DD);
        h8 qb = *(const h8*)(Qg + ((size_t)bh * TT + qb2 + qc) * DD);
        qf1 = hi ? qz : qa;
        qf2 = hi ? qz : qb;
    }

    fx16 O1, O2, zc;
    #pragma unroll
    for (int i = 0; i < 16; i++) { O1[i] = 0.0f; O2[i] = 0.0f; zc[i] = 0.0f; }

    const int vrow = (qc < 9) ? qc : 8;     // rows>=9 -> ones row (l trick)
    const int thr  = qc - 4 * hi;

    const __fp16* kgl = Kg + (size_t)bh * TT * DD;
    const __fp16* vgl = Vg + (size_t)bh * 9 * TT;
    __fp16* kld = KsS + h * KBS;            // wave-private
    __fp16* vld = VtS + h * VBS;
    const __fp16* kb = kld + qc * DD;
    const __fp16* vb = vld + vrow * VRS + 8 * hi;

    i4v kpre[4], vpre[5];
    {   // prefetch super-tile 0
        const i4v* ks = (const i4v*)kgl;
        #pragma unroll
        for (int r = 0; r < 4; r++) kpre[r] = ks[lane + 64 * r];
        #pragma unroll
        for (int r = 0; r < 5; r++) {
            int i = lane + 64 * r; if (i > 287) i = 287;
            vpre[r] = *(const i4v*)(vgl + (i >> 5) * TT + (i & 31) * 8);
        }
    }

    for (int sti = 0; sti < nst; sti++) {
        const int st = sti * 256;
        {   // commit prefetched tile to wave-private LDS
            i4v* kd = (i4v*)kld;
            #pragma unroll
            for (int r = 0; r < 4; r++) kd[lane + 64 * r] = kpre[r];
            #pragma unroll
            for (int r = 0; r < 5; r++) {
                const int i = lane + 64 * r;
                if (i < 288) *(i4v*)(vld + (i >> 5) * VRS + (i & 31) * 8) = vpre[r];
            }
        }
        if (sti + 1 < nst) {   // issue next tile's global loads (overlap compute)
            const int st2 = st + 256;
            const i4v* ks = (const i4v*)(kgl + (size_t)st2 * DD);
            #pragma unroll
            for (int r = 0; r < 4; r++) kpre[r] = ks[lane + 64 * r];
            #pragma unroll
            for (int r = 0; r < 5; r++) {
                int i = lane + 64 * r; if (i > 287) i = 287;
                vpre[r] = *(const i4v*)(vgl + (i >> 5) * TT + st2 + (i & 31) * 8);
            }
        }

        const int kend = min(st + 256, keys_needed);
        for (int kt = st; kt < kend; kt += 32) {
            const bool a1 = (kt <= qb1);            // wave-uniform
            h8 kf = *(const h8*)(kb + (kt - st) * DD);

            h8 P1[2], P2[2];
            if (a1) {
                fx16 S = __builtin_amdgcn_mfma_f32_32x32x16_f16(kf, qf1, zc, 0, 0, 0);
                makeP(S, kt == qb1, thr, hi, P1);
            }
            {
                fx16 S = __builtin_amdgcn_mfma_f32_32x32x16_f16(kf, qf2, zc, 0, 0, 0);
                makeP(S, kt == qb2, thr, hi, P2);
            }
            #pragma unroll
            for (int s = 0; s < 2; s++) {
                h8 vf = *(const h8*)(vb + (kt - st) + 16 * s);
                if (a1) O1 = __builtin_amdgcn_mfma_f32_32x32x16_f16(vf, P1[s], O1, 0, 0, 0);
                O2 = __builtin_amdgcn_mfma_f32_32x32x16_f16(vf, P2[s], O2, 0, 0, 0);
            }
        }
    }

    {   // z -> LDS: O[4] = l (ones-row); regs 0-3 = d0-3 (hi=0) / d4-7 (hi=1)
        const float i1 = 1.0f / O1[4], i2 = 1.0f / O2[4];
        float* z1 = &zbuf[qc * ZP + h * DD + 4 * hi];
        float* z2 = &zbuf[(32 + qc) * ZP + h * DD + 4 * hi];
        z1[0] = O1[0]*i1; z1[1] = O1[1]*i1; z1[2] = O1[2]*i1; z1[3] = O1[3]*i1;
        z2[0] = O2[0]*i2; z2[1] = O2[1]*i2; z2[2] = O2[2]*i2; z2[3] = O2[3]*i2;
    }
    __syncthreads();

    {   // in-block projection: wave = 8-col output segment (uniform Wp -> s_loads)
        const int seg = tid >> 6;
        const int r = tid & 63;             // rows 0-31 -> qg ip, 32-63 -> qg 63-ip
        float zr[CC];
        #pragma unroll
        for (int c = 0; c < CC; c++) zr[c] = zbuf[r * ZP + c];
        float o[DD];
        #pragma unroll
        for (int d = 0; d < DD; d++) {
            const int dd = seg * DD + d;
            float acc = bp[dd];
            #pragma unroll
            for (int c = 0; c < CC; c++) acc += zr[c] * Wp[dd * CC + c];
            o[d] = acc;
        }
        const int qglob = (r < 32) ? (ip * 32 + r) : ((63 - ip) * 32 + (r - 32));
        float* dst = out + ((size_t)b * TT + qglob) * CC + seg * DD;
        ((float4*)dst)[0] = make_float4(o[0], o[1], o[2], o[3]);
        ((float4*)dst)[1] = make_float4(o[4], o[5], o[6], o[7]);
    }
}

extern "C" void kernel_launch(void* const* d_in, const int* in_sizes, int n_in,
                              void* d_out, int out_size, void* d_ws, size_t ws_size,
                              hipStream_t stream) {
    const float* x  = (const float*)d_in[0];
    const float* Wq = (const float*)d_in[1];
    const float* bq = (const float*)d_in[2];
    const float* Wk = (const float*)d_in[3];
    const float* bk = (const float*)d_in[4];
    const float* Wv = (const float*)d_in[5];
    const float* bv = (const float*)d_in[6];
    const float* Wp = (const float*)d_in[7];
    const float* bp = (const float*)d_in[8];
    float* out = (float*)d_out;

    const size_t NE = (size_t)BB * HH * TT * DD;   // 1M
    __fp16* Qh = (__fp16*)d_ws;                    // 2 MB (pre-scaled)
    __fp16* Kh = Qh + NE;                          // 2 MB
    __fp16* Vt = Kh + NE;                          // 2.25 MB  [bh][9][T]

    qkv_kernel<<<dim3(BB * TT / 256, 12), 256, 0, stream>>>(x, Wq, bq, Wk, bk, Wv, bv, Qh, Kh, Vt);
    attn_kernel<<<dim3(BB * 32), 256, 0, stream>>>(Qh, Kh, Vt, Wp, bp, out);
}